// Round 1
// baseline (1063.141 us; speedup 1.0000x reference)
//
#include <hip/hip_runtime.h>
#include <hip/hip_bf16.h>
#include <math.h>

// Problem constants
#define BB 2
#define CC 1024
#define HH 64
#define WW 64
#define HWH (HH*WW)          // 4096
#define TT (BB*HWH)          // 8192 tokens
#define EE 8
#define FFN 1024

typedef __bf16 bf16x8 __attribute__((ext_vector_type(8)));
typedef __bf16 bf16x4 __attribute__((ext_vector_type(4)));
typedef float  f32x4  __attribute__((ext_vector_type(4)));

// ---------------------------------------------------------------------------
// Kernel 0: transpose + convert  hs (B,C,H,W) fp32  ->  X [T, C] bf16 row-major
// grid (HW/32, C/32, B), block 256
// ---------------------------------------------------------------------------
__global__ __launch_bounds__(256) void k_xpose(const float* __restrict__ hs,
                                               __bf16* __restrict__ X) {
    __shared__ float tile[32][33];
    const int hw0 = blockIdx.x * 32;
    const int c0  = blockIdx.y * 32;
    const int b   = blockIdx.z;
    const int tx  = threadIdx.x & 31;
    const int ty  = threadIdx.x >> 5;   // 0..7

    const float* src = hs + ((size_t)b * CC + c0) * HWH + hw0;
#pragma unroll
    for (int i = 0; i < 4; ++i) {
        tile[ty + i * 8][tx] = src[(size_t)(ty + i * 8) * HWH + tx];
    }
    __syncthreads();
    __bf16* dst = X + ((size_t)b * HWH + hw0) * CC + c0;
#pragma unroll
    for (int i = 0; i < 4; ++i) {
        const int hwl = ty + i * 8;
        dst[(size_t)hwl * CC + tx] = (__bf16)tile[tx][hwl];
    }
}

// ---------------------------------------------------------------------------
// Kernel 1: router.  Exact fp32 logits, softmax, top-2, renormalize.
// combine stored [E][T] fp32.  grid T/256, block 256.
// ---------------------------------------------------------------------------
__global__ __launch_bounds__(256) void k_router(const float* __restrict__ hs,
                                                const float* __restrict__ gate_w,
                                                float* __restrict__ comb) {
    __shared__ float g[EE * CC];   // 32 KB
    for (int i = threadIdx.x; i < EE * CC; i += 256) g[i] = gate_w[i];
    __syncthreads();

    const int t  = blockIdx.x * 256 + threadIdx.x;
    const int b  = t >> 12;          // t / 4096
    const int hw = t & 4095;
    const float* xp = hs + (size_t)b * CC * HWH + hw;

    float l[EE];
#pragma unroll
    for (int e = 0; e < EE; ++e) l[e] = 0.0f;

    for (int c = 0; c < CC; ++c) {
        const float xv = xp[(size_t)c * HWH];
#pragma unroll
        for (int e = 0; e < EE; ++e) l[e] += xv * g[e * CC + c];
    }

    // top-2 by logit (softmax is monotonic); jax top_k tie-break = lowest index
    int e1 = 0; float v1 = l[0];
#pragma unroll
    for (int e = 1; e < EE; ++e) { if (l[e] > v1) { v1 = l[e]; e1 = e; } }
    int e2 = -1; float v2 = -1e30f;
#pragma unroll
    for (int e = 0; e < EE; ++e) { if (e != e1 && l[e] > v2) { v2 = l[e]; e2 = e; } }

    // renormalized top-2 softmax weights (full-softmax normalizer cancels)
    const float p2 = __expf(v2 - v1);       // exp(l2-l1), p1 = 1
    const float rs = 1.0f / (1.0f + p2);
    const float c1 = rs;
    const float c2 = p2 * rs;

#pragma unroll
    for (int e = 0; e < EE; ++e) {
        comb[e * TT + t] = (e == e1) ? c1 : ((e == e2) ? c2 : 0.0f);
    }
}

// ---------------------------------------------------------------------------
// GEMM1: H[t,f] = gelu_exact(X @ W1^T) * (X @ W3^T), bf16 out.
// X [T,C] bf16, W1/W3 [FFN,C] fp32 (converted during staging).
// 128x128 tile, BK=32, 4 waves of 64x64.  grid (T/128, FFN/128)
// ---------------------------------------------------------------------------
__global__ __launch_bounds__(256, 2)
void k_gemm1(const __bf16* __restrict__ X, const float* __restrict__ W1,
             const float* __restrict__ W3, __bf16* __restrict__ H) {
    __shared__ __bf16 sA[128 * 40];
    __shared__ __bf16 sB1[128 * 40];
    __shared__ __bf16 sB3[128 * 40];

    const int tid  = threadIdx.x;
    const int lane = tid & 63;
    const int wave = tid >> 6;
    const int wm   = (wave & 1) * 64;
    const int wn   = (wave >> 1) * 64;
    const int m0   = blockIdx.x * 128;
    const int n0   = blockIdx.y * 128;
    const int l15  = lane & 15;
    const int lq   = lane >> 4;   // 0..3

    f32x4 acc1[4][4] = {};
    f32x4 acc3[4][4] = {};

    for (int kb = 0; kb < CC; kb += 32) {
        // stage A (bf16): 512 8-elem chunks over 256 threads
#pragma unroll
        for (int i = 0; i < 2; ++i) {
            const int q = tid + 256 * i;
            const int r = q >> 2, kc = (q & 3) * 8;
            *(bf16x8*)&sA[r * 40 + kc] =
                *(const bf16x8*)&X[(size_t)(m0 + r) * CC + kb + kc];
        }
        // stage B1/B3 (fp32 -> bf16): 1024 float4 chunks each over 256 threads
#pragma unroll
        for (int i = 0; i < 4; ++i) {
            const int q = tid + 256 * i;
            const int r = q >> 3, kc = (q & 7) * 4;
            const f32x4 a = *(const f32x4*)&W1[(size_t)(n0 + r) * CC + kb + kc];
            const f32x4 c = *(const f32x4*)&W3[(size_t)(n0 + r) * CC + kb + kc];
            bf16x4 pa, pc;
#pragma unroll
            for (int j = 0; j < 4; ++j) { pa[j] = (__bf16)a[j]; pc[j] = (__bf16)c[j]; }
            *(bf16x4*)&sB1[r * 40 + kc] = pa;
            *(bf16x4*)&sB3[r * 40 + kc] = pc;
        }
        __syncthreads();

        bf16x8 af[4], b1f[4], b3f[4];
#pragma unroll
        for (int i = 0; i < 4; ++i)
            af[i] = *(const bf16x8*)&sA[(wm + i * 16 + l15) * 40 + lq * 8];
#pragma unroll
        for (int j = 0; j < 4; ++j)
            b1f[j] = *(const bf16x8*)&sB1[(wn + j * 16 + l15) * 40 + lq * 8];
#pragma unroll
        for (int j = 0; j < 4; ++j)
            b3f[j] = *(const bf16x8*)&sB3[(wn + j * 16 + l15) * 40 + lq * 8];

#pragma unroll
        for (int i = 0; i < 4; ++i)
#pragma unroll
            for (int j = 0; j < 4; ++j) {
                acc1[i][j] = __builtin_amdgcn_mfma_f32_16x16x32_bf16(
                    af[i], b1f[j], acc1[i][j], 0, 0, 0);
                acc3[i][j] = __builtin_amdgcn_mfma_f32_16x16x32_bf16(
                    af[i], b3f[j], acc3[i][j], 0, 0, 0);
            }
        __syncthreads();
    }

    // epilogue: exact gelu(x) = 0.5*x*(1+erf(x/sqrt(2))), times w3 branch
#pragma unroll
    for (int i = 0; i < 4; ++i) {
        const int mb = m0 + wm + i * 16 + lq * 4;
#pragma unroll
        for (int j = 0; j < 4; ++j) {
            const int nb = n0 + wn + j * 16 + l15;
#pragma unroll
            for (int r = 0; r < 4; ++r) {
                const float a  = acc1[i][j][r];
                const float c  = acc3[i][j][r];
                const float ge = 0.5f * a * (1.0f + erff(a * 0.70710678118654752f));
                H[(size_t)(mb + r) * FFN + nb] = (__bf16)(ge * c);
            }
        }
    }
}

// ---------------------------------------------------------------------------
// GEMM2: out[t,c'] += comb[t] * (H @ W2^T)[t,c'], accumulated fp32 into
// (B,C,H,W)-layout d_out.  grid (T/128, C/128)
// ---------------------------------------------------------------------------
__global__ __launch_bounds__(256, 2)
void k_gemm2(const __bf16* __restrict__ H, const float* __restrict__ W2,
             const float* __restrict__ comb, float* __restrict__ out) {
    __shared__ __bf16 sA[128 * 40];
    __shared__ __bf16 sB[128 * 40];

    const int tid  = threadIdx.x;
    const int lane = tid & 63;
    const int wave = tid >> 6;
    const int wm   = (wave & 1) * 64;
    const int wn   = (wave >> 1) * 64;
    const int m0   = blockIdx.x * 128;
    const int n0   = blockIdx.y * 128;
    const int l15  = lane & 15;
    const int lq   = lane >> 4;

    f32x4 acc[4][4] = {};

    for (int kb = 0; kb < FFN; kb += 32) {
#pragma unroll
        for (int i = 0; i < 2; ++i) {
            const int q = tid + 256 * i;
            const int r = q >> 2, kc = (q & 3) * 8;
            *(bf16x8*)&sA[r * 40 + kc] =
                *(const bf16x8*)&H[(size_t)(m0 + r) * FFN + kb + kc];
        }
#pragma unroll
        for (int i = 0; i < 4; ++i) {
            const int q = tid + 256 * i;
            const int r = q >> 3, kc = (q & 7) * 4;
            const f32x4 a = *(const f32x4*)&W2[(size_t)(n0 + r) * FFN + kb + kc];
            bf16x4 pa;
#pragma unroll
            for (int j = 0; j < 4; ++j) pa[j] = (__bf16)a[j];
            *(bf16x4*)&sB[r * 40 + kc] = pa;
        }
        __syncthreads();

        bf16x8 af[4], bf[4];
#pragma unroll
        for (int i = 0; i < 4; ++i)
            af[i] = *(const bf16x8*)&sA[(wm + i * 16 + l15) * 40 + lq * 8];
#pragma unroll
        for (int j = 0; j < 4; ++j)
            bf[j] = *(const bf16x8*)&sB[(wn + j * 16 + l15) * 40 + lq * 8];

#pragma unroll
        for (int i = 0; i < 4; ++i)
#pragma unroll
            for (int j = 0; j < 4; ++j)
                acc[i][j] = __builtin_amdgcn_mfma_f32_16x16x32_bf16(
                    af[i], bf[j], acc[i][j], 0, 0, 0);
        __syncthreads();
    }

    // epilogue: weight by combine, accumulate into out (B,C,H,W) fp32.
    // frag reg r = 4 consecutive tokens at fixed c' -> contiguous float4 in out.
#pragma unroll
    for (int i = 0; i < 4; ++i) {
        const int tb = m0 + wm + i * 16 + lq * 4;
        const f32x4 cw = *(const f32x4*)&comb[tb];
        const int b  = tb >> 12;
        const int hw = tb & 4095;
        const size_t obase = (size_t)b * CC * HWH + hw;
#pragma unroll
        for (int j = 0; j < 4; ++j) {
            const int c = n0 + wn + j * 16 + l15;
            float* p = out + obase + (size_t)c * HWH;
            f32x4 o = *(f32x4*)p;
#pragma unroll
            for (int r = 0; r < 4; ++r) o[r] += acc[i][j][r] * cw[r];
            *(f32x4*)p = o;
        }
    }
}

// ---------------------------------------------------------------------------
extern "C" void kernel_launch(void* const* d_in, const int* in_sizes, int n_in,
                              void* d_out, int out_size, void* d_ws, size_t ws_size,
                              hipStream_t stream) {
    const float* hs     = (const float*)d_in[0];
    const float* gate_w = (const float*)d_in[1];
    const float* w1     = (const float*)d_in[2];
    const float* w2     = (const float*)d_in[3];
    const float* w3     = (const float*)d_in[4];
    float* out = (float*)d_out;

    // ws layout: X bf16 [T,C] (16 MB) | H bf16 [T,FFN] (16 MB) | comb fp32 [E][T]
    char* ws = (char*)d_ws;
    __bf16* X    = (__bf16*)ws;
    __bf16* Hbuf = (__bf16*)(ws + (size_t)TT * CC * 2);
    float*  comb = (float*)(ws + (size_t)TT * CC * 2 + (size_t)TT * FFN * 2);

    hipMemsetAsync(d_out, 0, (size_t)out_size * sizeof(float), stream);

    k_xpose<<<dim3(HWH / 32, CC / 32, BB), 256, 0, stream>>>(hs, X);
    k_router<<<TT / 256, 256, 0, stream>>>(hs, gate_w, comb);

    for (int e = 0; e < EE; ++e) {
        const size_t wo = (size_t)e * FFN * CC;
        k_gemm1<<<dim3(TT / 128, FFN / 128), 256, 0, stream>>>(
            X, w1 + wo, w3 + wo, Hbuf);
        k_gemm2<<<dim3(TT / 128, CC / 128), 256, 0, stream>>>(
            Hbuf, w2 + wo, comb + (size_t)e * TT, out);
    }
}

// Round 2
// 514.120 us; speedup vs baseline: 2.0679x; 2.0679x over previous
//
#include <hip/hip_runtime.h>
#include <hip/hip_bf16.h>
#include <math.h>

// Problem constants
#define BB 2
#define CC 1024
#define HH 64
#define WW 64
#define HWH (HH*WW)          // 4096
#define TT (BB*HWH)          // 8192 tokens
#define EE 8
#define FFN 1024
#define HCAP 17408           // sum_e ceil(cnt_e/128)*128 <= 16384 + 8*127 = 17400

typedef __bf16 bf16x8 __attribute__((ext_vector_type(8)));
typedef __bf16 bf16x4 __attribute__((ext_vector_type(4)));
typedef float  f32x4  __attribute__((ext_vector_type(4)));

// ---------------------------------------------------------------------------
// Kernel 0: transpose + convert  hs (B,C,H,W) fp32  ->  X [T, C] bf16 row-major
// ---------------------------------------------------------------------------
__global__ __launch_bounds__(256) void k_xpose(const float* __restrict__ hs,
                                               __bf16* __restrict__ X) {
    __shared__ float tile[32][33];
    const int hw0 = blockIdx.x * 32;
    const int c0  = blockIdx.y * 32;
    const int b   = blockIdx.z;
    const int tx  = threadIdx.x & 31;
    const int ty  = threadIdx.x >> 5;   // 0..7

    const float* src = hs + ((size_t)b * CC + c0) * HWH + hw0;
#pragma unroll
    for (int i = 0; i < 4; ++i)
        tile[ty + i * 8][tx] = src[(size_t)(ty + i * 8) * HWH + tx];
    __syncthreads();
    __bf16* dst = X + ((size_t)b * HWH + hw0) * CC + c0;
#pragma unroll
    for (int i = 0; i < 4; ++i) {
        const int hwl = ty + i * 8;
        dst[(size_t)hwl * CC + tx] = (__bf16)tile[tx][hwl];
    }
}

// ---------------------------------------------------------------------------
// Kernel 1: router. Exact fp32 logits, top-2, renormalize; build expert lists.
// cnt[E] pre-zeroed. idxl[e*T + pos] = token. Per-token records for combine.
// ---------------------------------------------------------------------------
__global__ __launch_bounds__(256) void k_router(const float* __restrict__ hs,
                                                const float* __restrict__ gate_w,
                                                int* __restrict__ cnt,
                                                int* __restrict__ idxl,
                                                int* __restrict__ tokE,
                                                int* __restrict__ tokP,
                                                float* __restrict__ tokW) {
    __shared__ float g[EE * CC];   // 32 KB
    for (int i = threadIdx.x; i < EE * CC; i += 256) g[i] = gate_w[i];
    __syncthreads();

    const int t  = blockIdx.x * 256 + threadIdx.x;
    const int b  = t >> 12;
    const int hw = t & 4095;
    const float* xp = hs + (size_t)b * CC * HWH + hw;

    float l[EE];
#pragma unroll
    for (int e = 0; e < EE; ++e) l[e] = 0.0f;

    for (int c = 0; c < CC; ++c) {
        const float xv = xp[(size_t)c * HWH];
#pragma unroll
        for (int e = 0; e < EE; ++e) l[e] += xv * g[e * CC + c];
    }

    // top-2 by logit (softmax monotonic); tie-break = lowest index via strict >
    int e1 = 0; float v1 = l[0];
#pragma unroll
    for (int e = 1; e < EE; ++e) { if (l[e] > v1) { v1 = l[e]; e1 = e; } }
    int e2 = -1; float v2 = -1e30f;
#pragma unroll
    for (int e = 0; e < EE; ++e) { if (e != e1 && l[e] > v2) { v2 = l[e]; e2 = e; } }

    const float p2 = __expf(v2 - v1);
    const float rs = 1.0f / (1.0f + p2);

    const int p1pos = atomicAdd(&cnt[e1], 1);
    idxl[e1 * TT + p1pos] = t;
    const int p2pos = atomicAdd(&cnt[e2], 1);
    idxl[e2 * TT + p2pos] = t;

    tokE[t] = e1 | (e2 << 8);
    tokP[2 * t]     = p1pos;
    tokP[2 * t + 1] = p2pos;
    tokW[2 * t]     = rs;
    tokW[2 * t + 1] = p2 * rs;
}

// ---------------------------------------------------------------------------
// Kernel 2: padded prefix offsets (single tiny block)
// ---------------------------------------------------------------------------
__global__ void k_offsets(const int* __restrict__ cnt, int* __restrict__ off) {
    if (threadIdx.x == 0) {
        int a = 0;
#pragma unroll
        for (int e = 0; e < EE; ++e) {
            off[e] = a;
            a += ((cnt[e] + 127) >> 7) << 7;
        }
    }
}

// ---------------------------------------------------------------------------
// GEMM1 (sparse, grouped): for expert e, gathered rows, H = gelu(X@W1^T)*(X@W3^T)
// grid (FFN/128, 64, E), early exit past this expert's count.
// ---------------------------------------------------------------------------
__global__ __launch_bounds__(256, 2)
void k_gemm1(const __bf16* __restrict__ X, const float* __restrict__ w1,
             const float* __restrict__ w3, const int* __restrict__ cnt,
             const int* __restrict__ off, const int* __restrict__ idxl,
             __bf16* __restrict__ H) {
    const int e     = blockIdx.z;
    const int mt128 = blockIdx.y * 128;
    const int cntE  = cnt[e];
    if (mt128 >= cntE) return;
    const int goff  = off[e];
    const int n0    = blockIdx.x * 128;
    const float* W1 = w1 + (size_t)e * FFN * CC;
    const float* W3 = w3 + (size_t)e * FFN * CC;

    __shared__ __bf16 sA[128 * 40];
    __shared__ __bf16 sB1[128 * 40];
    __shared__ __bf16 sB3[128 * 40];

    const int tid  = threadIdx.x;
    const int lane = tid & 63;
    const int wave = tid >> 6;
    const int wm   = (wave & 1) * 64;
    const int wn   = (wave >> 1) * 64;
    const int l15  = lane & 15;
    const int lq   = lane >> 4;

    // gather-row pointers for A staging (2 rows per thread), clamped to count
    const int rA  = tid >> 2;
    const int kcA = (tid & 3) * 8;
    int p0 = mt128 + rA;       if (p0 > cntE - 1) p0 = cntE - 1;
    int p1 = mt128 + rA + 64;  if (p1 > cntE - 1) p1 = cntE - 1;
    const __bf16* xrow0 = X + (size_t)idxl[e * TT + p0] * CC;
    const __bf16* xrow1 = X + (size_t)idxl[e * TT + p1] * CC;

    f32x4 acc1[4][4] = {};
    f32x4 acc3[4][4] = {};

    for (int kb = 0; kb < CC; kb += 32) {
        *(bf16x8*)&sA[rA * 40 + kcA]        = *(const bf16x8*)&xrow0[kb + kcA];
        *(bf16x8*)&sA[(rA + 64) * 40 + kcA] = *(const bf16x8*)&xrow1[kb + kcA];
#pragma unroll
        for (int i = 0; i < 4; ++i) {
            const int q = tid + 256 * i;
            const int r = q >> 3, kc = (q & 7) * 4;
            const f32x4 a = *(const f32x4*)&W1[(size_t)(n0 + r) * CC + kb + kc];
            const f32x4 c = *(const f32x4*)&W3[(size_t)(n0 + r) * CC + kb + kc];
            bf16x4 pa, pc;
#pragma unroll
            for (int j = 0; j < 4; ++j) { pa[j] = (__bf16)a[j]; pc[j] = (__bf16)c[j]; }
            *(bf16x4*)&sB1[r * 40 + kc] = pa;
            *(bf16x4*)&sB3[r * 40 + kc] = pc;
        }
        __syncthreads();

        bf16x8 af[4], b1f[4], b3f[4];
#pragma unroll
        for (int i = 0; i < 4; ++i)
            af[i] = *(const bf16x8*)&sA[(wm + i * 16 + l15) * 40 + lq * 8];
#pragma unroll
        for (int j = 0; j < 4; ++j)
            b1f[j] = *(const bf16x8*)&sB1[(wn + j * 16 + l15) * 40 + lq * 8];
#pragma unroll
        for (int j = 0; j < 4; ++j)
            b3f[j] = *(const bf16x8*)&sB3[(wn + j * 16 + l15) * 40 + lq * 8];

#pragma unroll
        for (int i = 0; i < 4; ++i)
#pragma unroll
            for (int j = 0; j < 4; ++j) {
                acc1[i][j] = __builtin_amdgcn_mfma_f32_16x16x32_bf16(
                    af[i], b1f[j], acc1[i][j], 0, 0, 0);
                acc3[i][j] = __builtin_amdgcn_mfma_f32_16x16x32_bf16(
                    af[i], b3f[j], acc3[i][j], 0, 0, 0);
            }
        __syncthreads();
    }

    // epilogue: exact gelu * w3-branch -> packed H rows
#pragma unroll
    for (int i = 0; i < 4; ++i) {
        const int gb = goff + mt128 + wm + i * 16 + lq * 4;
#pragma unroll
        for (int j = 0; j < 4; ++j) {
            const int nb = n0 + wn + j * 16 + l15;
#pragma unroll
            for (int r = 0; r < 4; ++r) {
                const float a  = acc1[i][j][r];
                const float c  = acc3[i][j][r];
                const float ge = 0.5f * a * (1.0f + erff(a * 0.70710678118654752f));
                H[(size_t)(gb + r) * FFN + nb] = (__bf16)(ge * c);
            }
        }
    }
}

// ---------------------------------------------------------------------------
// GEMM2 (sparse, grouped): Z = H @ W2^T over packed rows, bf16 out (packed).
// grid (C/128, 64, E)
// ---------------------------------------------------------------------------
__global__ __launch_bounds__(256, 2)
void k_gemm2(const __bf16* __restrict__ H, const float* __restrict__ w2,
             const int* __restrict__ cnt, const int* __restrict__ off,
             __bf16* __restrict__ Z) {
    const int e     = blockIdx.z;
    const int mt128 = blockIdx.y * 128;
    const int cntE  = cnt[e];
    if (mt128 >= cntE) return;
    const int goff  = off[e];
    const int n0    = blockIdx.x * 128;
    const float* W2 = w2 + (size_t)e * CC * FFN;
    const __bf16* Arows = H + (size_t)(goff + mt128) * FFN;

    __shared__ __bf16 sA[128 * 40];
    __shared__ __bf16 sB[128 * 40];

    const int tid  = threadIdx.x;
    const int lane = tid & 63;
    const int wave = tid >> 6;
    const int wm   = (wave & 1) * 64;
    const int wn   = (wave >> 1) * 64;
    const int l15  = lane & 15;
    const int lq   = lane >> 4;

    f32x4 acc[4][4] = {};

    for (int kb = 0; kb < FFN; kb += 32) {
#pragma unroll
        for (int i = 0; i < 2; ++i) {
            const int q = tid + 256 * i;
            const int r = q >> 2, kc = (q & 3) * 8;
            *(bf16x8*)&sA[r * 40 + kc] =
                *(const bf16x8*)&Arows[(size_t)r * FFN + kb + kc];
        }
#pragma unroll
        for (int i = 0; i < 4; ++i) {
            const int q = tid + 256 * i;
            const int r = q >> 3, kc = (q & 7) * 4;
            const f32x4 a = *(const f32x4*)&W2[(size_t)(n0 + r) * FFN + kb + kc];
            bf16x4 pa;
#pragma unroll
            for (int j = 0; j < 4; ++j) pa[j] = (__bf16)a[j];
            *(bf16x4*)&sB[r * 40 + kc] = pa;
        }
        __syncthreads();

        bf16x8 af[4], bf[4];
#pragma unroll
        for (int i = 0; i < 4; ++i)
            af[i] = *(const bf16x8*)&sA[(wm + i * 16 + l15) * 40 + lq * 8];
#pragma unroll
        for (int j = 0; j < 4; ++j)
            bf[j] = *(const bf16x8*)&sB[(wn + j * 16 + l15) * 40 + lq * 8];

#pragma unroll
        for (int i = 0; i < 4; ++i)
#pragma unroll
            for (int j = 0; j < 4; ++j)
                acc[i][j] = __builtin_amdgcn_mfma_f32_16x16x32_bf16(
                    af[i], bf[j], acc[i][j], 0, 0, 0);
        __syncthreads();
    }

#pragma unroll
    for (int i = 0; i < 4; ++i) {
        const int gb = goff + mt128 + wm + i * 16 + lq * 4;
#pragma unroll
        for (int j = 0; j < 4; ++j) {
            const int c = n0 + wn + j * 16 + l15;
#pragma unroll
            for (int r = 0; r < 4; ++r)
                Z[(size_t)(gb + r) * CC + c] = (__bf16)acc[i][j][r];
        }
    }
}

// ---------------------------------------------------------------------------
// Kernel 5: combine + transpose to (B,C,H,W).
// out[t,c] = w1*Z[r1,c] + w2*Z[r2,c]; 32x32 LDS tile for transposed store.
// grid (T/32, C/32), block 256.
// ---------------------------------------------------------------------------
__global__ __launch_bounds__(256) void k_combine(const __bf16* __restrict__ Z,
                                                 const int* __restrict__ off,
                                                 const int* __restrict__ tokE,
                                                 const int* __restrict__ tokP,
                                                 const float* __restrict__ tokW,
                                                 float* __restrict__ out) {
    __shared__ float tile[32][33];
    const int t0 = blockIdx.x * 32;
    const int c0 = blockIdx.y * 32;
    const int tx = threadIdx.x & 31;
    const int ty = threadIdx.x >> 5;   // 0..7

#pragma unroll
    for (int i = 0; i < 4; ++i) {
        const int tl = ty + 8 * i;
        const int t  = t0 + tl;
        const int ee = tokE[t];
        const int e1 = ee & 0xff, e2 = ee >> 8;
        const int r1 = off[e1] + tokP[2 * t];
        const int r2 = off[e2] + tokP[2 * t + 1];
        const float v = tokW[2 * t]     * (float)Z[(size_t)r1 * CC + c0 + tx]
                      + tokW[2 * t + 1] * (float)Z[(size_t)r2 * CC + c0 + tx];
        tile[tl][tx] = v;
    }
    __syncthreads();

    const int b   = t0 >> 12;
    const int hw0 = t0 & 4095;
#pragma unroll
    for (int i = 0; i < 4; ++i) {
        const int cl = ty + 8 * i;
        out[(size_t)b * CC * HWH + (size_t)(c0 + cl) * HWH + hw0 + tx] = tile[tx][cl];
    }
}

// ---------------------------------------------------------------------------
extern "C" void kernel_launch(void* const* d_in, const int* in_sizes, int n_in,
                              void* d_out, int out_size, void* d_ws, size_t ws_size,
                              hipStream_t stream) {
    const float* hs     = (const float*)d_in[0];
    const float* gate_w = (const float*)d_in[1];
    const float* w1     = (const float*)d_in[2];
    const float* w2     = (const float*)d_in[3];
    const float* w3     = (const float*)d_in[4];
    float* out = (float*)d_out;

    // ws layout
    char* ws = (char*)d_ws;
    __bf16* X    = (__bf16*)ws;                                   // 16 MB
    __bf16* Hbuf = (__bf16*)(ws + (size_t)TT * CC * 2);           // 35.65 MB
    __bf16* Zbuf = (__bf16*)(ws + (size_t)TT * CC * 2
                                + (size_t)HCAP * FFN * 2);        // 35.65 MB
    char* p = ws + (size_t)TT * CC * 2 + 2 * (size_t)HCAP * FFN * 2;
    int*   idxl = (int*)p;            p += (size_t)EE * TT * 4;   // 256 KB
    int*   tokE = (int*)p;            p += (size_t)TT * 4;
    int*   tokP = (int*)p;            p += (size_t)2 * TT * 4;
    float* tokW = (float*)p;          p += (size_t)2 * TT * 4;
    int*   cnt  = (int*)p;            p += 256;
    int*   off  = (int*)p;

    hipMemsetAsync(cnt, 0, EE * sizeof(int), stream);

    k_xpose<<<dim3(HWH / 32, CC / 32, BB), 256, 0, stream>>>(hs, X);
    k_router<<<TT / 256, 256, 0, stream>>>(hs, gate_w, cnt, idxl, tokE, tokP, tokW);
    k_offsets<<<1, 64, 0, stream>>>(cnt, off);

    k_gemm1<<<dim3(FFN / 128, TT / 128, EE), 256, 0, stream>>>(
        X, w1, w3, cnt, off, idxl, Hbuf);
    k_gemm2<<<dim3(CC / 128, TT / 128, EE), 256, 0, stream>>>(
        Hbuf, w2, cnt, off, Zbuf);
    k_combine<<<dim3(TT / 32, CC / 32), 256, 0, stream>>>(
        Zbuf, off, tokE, tokP, tokW, out);
}

// Round 3
// 436.699 us; speedup vs baseline: 2.4345x; 1.1773x over previous
//
#include <hip/hip_runtime.h>
#include <hip/hip_bf16.h>
#include <math.h>

// Problem constants
#define BB 2
#define CC 1024
#define HH 64
#define WW 64
#define HWH (HH*WW)          // 4096
#define TT (BB*HWH)          // 8192 tokens
#define EE 8
#define FFN 1024
#define HCAP 17408           // sum_e ceil(cnt_e/128)*128 <= 16384 + 8*127 = 17400

typedef __bf16 bf16x8 __attribute__((ext_vector_type(8)));
typedef __bf16 bf16x4 __attribute__((ext_vector_type(4)));
typedef float  f32x4  __attribute__((ext_vector_type(4)));

// async global->LDS, 16B per lane. LDS dest = wave-uniform base + lane*16.
__device__ __forceinline__ void gl_lds16(const __bf16* g, __bf16* l) {
    __builtin_amdgcn_global_load_lds(
        (const __attribute__((address_space(1))) void*)g,
        (__attribute__((address_space(3))) void*)l, 16, 0, 0);
}

// ---------------------------------------------------------------------------
// Kernel 0: transpose + convert  hs (B,C,H,W) fp32  ->  X [T, C] bf16 row-major
// ---------------------------------------------------------------------------
__global__ __launch_bounds__(256) void k_xpose(const float* __restrict__ hs,
                                               __bf16* __restrict__ X) {
    __shared__ float tile[32][33];
    const int hw0 = blockIdx.x * 32;
    const int c0  = blockIdx.y * 32;
    const int b   = blockIdx.z;
    const int tx  = threadIdx.x & 31;
    const int ty  = threadIdx.x >> 5;

    const float* src = hs + ((size_t)b * CC + c0) * HWH + hw0;
#pragma unroll
    for (int i = 0; i < 4; ++i)
        tile[ty + i * 8][tx] = src[(size_t)(ty + i * 8) * HWH + tx];
    __syncthreads();
    __bf16* dst = X + ((size_t)b * HWH + hw0) * CC + c0;
#pragma unroll
    for (int i = 0; i < 4; ++i) {
        const int hwl = ty + i * 8;
        dst[(size_t)hwl * CC + tx] = (__bf16)tile[tx][hwl];
    }
}

// ---------------------------------------------------------------------------
// Kernel 0b: fp32 -> bf16 weight conversion (w1, w2, w3).
// grid (EE*FFN*CC/1024, 3), block 256, 4 elems/thread.
// ---------------------------------------------------------------------------
__global__ __launch_bounds__(256) void k_cvt(const float* __restrict__ s0,
                                             const float* __restrict__ s1,
                                             const float* __restrict__ s2,
                                             __bf16* __restrict__ d0,
                                             __bf16* __restrict__ d1,
                                             __bf16* __restrict__ d2) {
    const float* s = (blockIdx.y == 0) ? s0 : ((blockIdx.y == 1) ? s1 : s2);
    __bf16*      d = (blockIdx.y == 0) ? d0 : ((blockIdx.y == 1) ? d1 : d2);
    const size_t i = ((size_t)blockIdx.x * 256 + threadIdx.x) * 4;
    const f32x4 v = *(const f32x4*)&s[i];
    bf16x4 o;
#pragma unroll
    for (int j = 0; j < 4; ++j) o[j] = (__bf16)v[j];
    *(bf16x4*)&d[i] = o;
}

// ---------------------------------------------------------------------------
// Kernel 1: router, K-split by 4. Exact fp32 logits, top-2, renormalize,
// expert lists via atomics. grid TT/64 blocks, 256 threads.
// ---------------------------------------------------------------------------
__global__ __launch_bounds__(256) void k_router(const float* __restrict__ hs,
                                                const float* __restrict__ gate_w,
                                                int* __restrict__ cnt,
                                                int* __restrict__ idxl,
                                                int* __restrict__ tokE,
                                                int* __restrict__ tokP,
                                                float* __restrict__ tokW) {
    __shared__ float g[EE * CC];        // 32 KB
    __shared__ float part[3][64][9];    // padded stride 9: no bank conflicts
    for (int i = threadIdx.x; i < EE * CC; i += 256) g[i] = gate_w[i];
    __syncthreads();

    const int tl = threadIdx.x & 63;
    const int q  = threadIdx.x >> 6;    // channel quarter 0..3 (== wave id)
    const int t  = blockIdx.x * 64 + tl;
    const int b  = t >> 12;
    const int hw = t & 4095;
    const float* xp = hs + (size_t)b * CC * HWH + hw;

    float l[EE];
#pragma unroll
    for (int e = 0; e < EE; ++e) l[e] = 0.0f;

    const int c0 = q * 256;
    for (int c = c0; c < c0 + 256; ++c) {
        const float xv = xp[(size_t)c * HWH];
#pragma unroll
        for (int e = 0; e < EE; ++e) l[e] += xv * g[e * CC + c];
    }

    if (q > 0) {
#pragma unroll
        for (int e = 0; e < EE; ++e) part[q - 1][tl][e] = l[e];
    }
    __syncthreads();
    if (q != 0) return;

#pragma unroll
    for (int e = 0; e < EE; ++e)
        l[e] += part[0][tl][e] + part[1][tl][e] + part[2][tl][e];

    // top-2 by logit (softmax monotonic); tie-break = lowest index via strict >
    int e1 = 0; float v1 = l[0];
#pragma unroll
    for (int e = 1; e < EE; ++e) { if (l[e] > v1) { v1 = l[e]; e1 = e; } }
    int e2 = -1; float v2 = -1e30f;
#pragma unroll
    for (int e = 0; e < EE; ++e) { if (e != e1 && l[e] > v2) { v2 = l[e]; e2 = e; } }

    const float p2 = __expf(v2 - v1);
    const float rs = 1.0f / (1.0f + p2);

    const int p1pos = atomicAdd(&cnt[e1], 1);
    idxl[e1 * TT + p1pos] = t;
    const int p2pos = atomicAdd(&cnt[e2], 1);
    idxl[e2 * TT + p2pos] = t;

    tokE[t] = e1 | (e2 << 8);
    tokP[2 * t]     = p1pos;
    tokP[2 * t + 1] = p2pos;
    tokW[2 * t]     = rs;
    tokW[2 * t + 1] = p2 * rs;
}

// ---------------------------------------------------------------------------
// Kernel 2: padded prefix offsets (single tiny block)
// ---------------------------------------------------------------------------
__global__ void k_offsets(const int* __restrict__ cnt, int* __restrict__ off) {
    if (threadIdx.x == 0) {
        int a = 0;
#pragma unroll
        for (int e = 0; e < EE; ++e) {
            off[e] = a;
            a += ((cnt[e] + 127) >> 7) << 7;
        }
    }
}

// ---------------------------------------------------------------------------
// GEMM1 (sparse, grouped, async-staged): H = gelu(X@W1^T)*(X@W3^T), bf16.
// 128x128 tile, BK=32, unpadded LDS (global_load_lds requires lane-order
// contiguity). grid (FFN/128, 64, E), early exit past expert's count.
// ---------------------------------------------------------------------------
__global__ __launch_bounds__(256, 2)
void k_gemm1(const __bf16* __restrict__ X, const __bf16* __restrict__ w1b,
             const __bf16* __restrict__ w3b, const int* __restrict__ cnt,
             const int* __restrict__ off, const int* __restrict__ idxl,
             __bf16* __restrict__ H) {
    const int e     = blockIdx.z;
    const int mt128 = blockIdx.y * 128;
    const int cntE  = cnt[e];
    if (mt128 >= cntE) return;
    const int goff  = off[e];
    const int n0    = blockIdx.x * 128;
    const __bf16* W1 = w1b + (size_t)e * FFN * CC;
    const __bf16* W3 = w3b + (size_t)e * FFN * CC;

    __shared__ __bf16 sA[128 * 32];    // 8 KB each, unpadded
    __shared__ __bf16 sB1[128 * 32];
    __shared__ __bf16 sB3[128 * 32];

    const int tid  = threadIdx.x;
    const int lane = tid & 63;
    const int wave = tid >> 6;
    const int wm   = (wave & 1) * 64;
    const int wn   = (wave >> 1) * 64;
    const int l15  = lane & 15;
    const int lq   = lane >> 4;
    const int l4   = lane >> 2;          // row within 16-row group
    const int c8   = (lane & 3) * 8;     // col offset (elements)

    // per-lane global row pointers (gathered, clamped) + wave-uniform LDS bases
    int p0 = mt128 + wave * 32 + l4;      if (p0 > cntE - 1) p0 = cntE - 1;
    int p1 = mt128 + wave * 32 + 16 + l4; if (p1 > cntE - 1) p1 = cntE - 1;
    const __bf16* ga0 = X + (size_t)idxl[e * TT + p0] * CC + c8;
    const __bf16* ga1 = X + (size_t)idxl[e * TT + p1] * CC + c8;
    const __bf16* gb10 = W1 + (size_t)(n0 + wave * 32 + l4) * CC + c8;
    const __bf16* gb11 = W1 + (size_t)(n0 + wave * 32 + 16 + l4) * CC + c8;
    const __bf16* gb30 = W3 + (size_t)(n0 + wave * 32 + l4) * CC + c8;
    const __bf16* gb31 = W3 + (size_t)(n0 + wave * 32 + 16 + l4) * CC + c8;
    __bf16* la0  = &sA [(wave * 32) * 32];
    __bf16* la1  = &sA [(wave * 32 + 16) * 32];
    __bf16* lb10 = &sB1[(wave * 32) * 32];
    __bf16* lb11 = &sB1[(wave * 32 + 16) * 32];
    __bf16* lb30 = &sB3[(wave * 32) * 32];
    __bf16* lb31 = &sB3[(wave * 32 + 16) * 32];

    f32x4 acc1[4][4] = {};
    f32x4 acc3[4][4] = {};

    for (int kb = 0; kb < CC; kb += 32) {
        gl_lds16(ga0 + kb, la0);
        gl_lds16(ga1 + kb, la1);
        gl_lds16(gb10 + kb, lb10);
        gl_lds16(gb11 + kb, lb11);
        gl_lds16(gb30 + kb, lb30);
        gl_lds16(gb31 + kb, lb31);
        __syncthreads();

        bf16x8 af[4], b1f[4], b3f[4];
#pragma unroll
        for (int i = 0; i < 4; ++i)
            af[i] = *(const bf16x8*)&sA[(wm + i * 16 + l15) * 32 + lq * 8];
#pragma unroll
        for (int j = 0; j < 4; ++j)
            b1f[j] = *(const bf16x8*)&sB1[(wn + j * 16 + l15) * 32 + lq * 8];
#pragma unroll
        for (int j = 0; j < 4; ++j)
            b3f[j] = *(const bf16x8*)&sB3[(wn + j * 16 + l15) * 32 + lq * 8];

#pragma unroll
        for (int i = 0; i < 4; ++i)
#pragma unroll
            for (int j = 0; j < 4; ++j) {
                acc1[i][j] = __builtin_amdgcn_mfma_f32_16x16x32_bf16(
                    af[i], b1f[j], acc1[i][j], 0, 0, 0);
                acc3[i][j] = __builtin_amdgcn_mfma_f32_16x16x32_bf16(
                    af[i], b3f[j], acc3[i][j], 0, 0, 0);
            }
        __syncthreads();
    }

    // epilogue: exact gelu * w3-branch -> packed H rows
#pragma unroll
    for (int i = 0; i < 4; ++i) {
        const int gb = goff + mt128 + wm + i * 16 + lq * 4;
#pragma unroll
        for (int j = 0; j < 4; ++j) {
            const int nb = n0 + wn + j * 16 + l15;
#pragma unroll
            for (int r = 0; r < 4; ++r) {
                const float a  = acc1[i][j][r];
                const float c  = acc3[i][j][r];
                const float ge = 0.5f * a * (1.0f + erff(a * 0.70710678118654752f));
                H[(size_t)(gb + r) * FFN + nb] = (__bf16)(ge * c);
            }
        }
    }
}

// ---------------------------------------------------------------------------
// GEMM2 (sparse, grouped, async-staged): Z = H @ W2^T, packed bf16.
// grid (C/128, 64, E)
// ---------------------------------------------------------------------------
__global__ __launch_bounds__(256, 2)
void k_gemm2(const __bf16* __restrict__ H, const __bf16* __restrict__ w2b,
             const int* __restrict__ cnt, const int* __restrict__ off,
             __bf16* __restrict__ Z) {
    const int e     = blockIdx.z;
    const int mt128 = blockIdx.y * 128;
    const int cntE  = cnt[e];
    if (mt128 >= cntE) return;
    const int goff  = off[e];
    const int n0    = blockIdx.x * 128;
    const __bf16* W2 = w2b + (size_t)e * CC * FFN;
    const __bf16* Arows = H + (size_t)(goff + mt128) * FFN;

    __shared__ __bf16 sA[128 * 32];
    __shared__ __bf16 sB[128 * 32];

    const int tid  = threadIdx.x;
    const int lane = tid & 63;
    const int wave = tid >> 6;
    const int wm   = (wave & 1) * 64;
    const int wn   = (wave >> 1) * 64;
    const int l15  = lane & 15;
    const int lq   = lane >> 4;
    const int l4   = lane >> 2;
    const int c8   = (lane & 3) * 8;

    const __bf16* ga0 = Arows + (size_t)(wave * 32 + l4) * FFN + c8;
    const __bf16* ga1 = Arows + (size_t)(wave * 32 + 16 + l4) * FFN + c8;
    const __bf16* gb0 = W2 + (size_t)(n0 + wave * 32 + l4) * FFN + c8;
    const __bf16* gb1 = W2 + (size_t)(n0 + wave * 32 + 16 + l4) * FFN + c8;
    __bf16* la0 = &sA[(wave * 32) * 32];
    __bf16* la1 = &sA[(wave * 32 + 16) * 32];
    __bf16* lb0 = &sB[(wave * 32) * 32];
    __bf16* lb1 = &sB[(wave * 32 + 16) * 32];

    f32x4 acc[4][4] = {};

    for (int kb = 0; kb < FFN; kb += 32) {
        gl_lds16(ga0 + kb, la0);
        gl_lds16(ga1 + kb, la1);
        gl_lds16(gb0 + kb, lb0);
        gl_lds16(gb1 + kb, lb1);
        __syncthreads();

        bf16x8 af[4], bf[4];
#pragma unroll
        for (int i = 0; i < 4; ++i)
            af[i] = *(const bf16x8*)&sA[(wm + i * 16 + l15) * 32 + lq * 8];
#pragma unroll
        for (int j = 0; j < 4; ++j)
            bf[j] = *(const bf16x8*)&sB[(wn + j * 16 + l15) * 32 + lq * 8];

#pragma unroll
        for (int i = 0; i < 4; ++i)
#pragma unroll
            for (int j = 0; j < 4; ++j)
                acc[i][j] = __builtin_amdgcn_mfma_f32_16x16x32_bf16(
                    af[i], bf[j], acc[i][j], 0, 0, 0);
        __syncthreads();
    }

#pragma unroll
    for (int i = 0; i < 4; ++i) {
        const int gb = goff + mt128 + wm + i * 16 + lq * 4;
#pragma unroll
        for (int j = 0; j < 4; ++j) {
            const int c = n0 + wn + j * 16 + l15;
#pragma unroll
            for (int r = 0; r < 4; ++r)
                Z[(size_t)(gb + r) * CC + c] = (__bf16)acc[i][j][r];
        }
    }
}

// ---------------------------------------------------------------------------
// Kernel 5: combine + transpose to (B,C,H,W).
// ---------------------------------------------------------------------------
__global__ __launch_bounds__(256) void k_combine(const __bf16* __restrict__ Z,
                                                 const int* __restrict__ off,
                                                 const int* __restrict__ tokE,
                                                 const int* __restrict__ tokP,
                                                 const float* __restrict__ tokW,
                                                 float* __restrict__ out) {
    __shared__ float tile[32][33];
    const int t0 = blockIdx.x * 32;
    const int c0 = blockIdx.y * 32;
    const int tx = threadIdx.x & 31;
    const int ty = threadIdx.x >> 5;

#pragma unroll
    for (int i = 0; i < 4; ++i) {
        const int tl = ty + 8 * i;
        const int t  = t0 + tl;
        const int ee = tokE[t];
        const int e1 = ee & 0xff, e2 = ee >> 8;
        const int r1 = off[e1] + tokP[2 * t];
        const int r2 = off[e2] + tokP[2 * t + 1];
        const float v = tokW[2 * t]     * (float)Z[(size_t)r1 * CC + c0 + tx]
                      + tokW[2 * t + 1] * (float)Z[(size_t)r2 * CC + c0 + tx];
        tile[tl][tx] = v;
    }
    __syncthreads();

    const int b   = t0 >> 12;
    const int hw0 = t0 & 4095;
#pragma unroll
    for (int i = 0; i < 4; ++i) {
        const int cl = ty + 8 * i;
        out[(size_t)b * CC * HWH + (size_t)(c0 + cl) * HWH + hw0 + tx] = tile[tx][cl];
    }
}

// ---------------------------------------------------------------------------
extern "C" void kernel_launch(void* const* d_in, const int* in_sizes, int n_in,
                              void* d_out, int out_size, void* d_ws, size_t ws_size,
                              hipStream_t stream) {
    const float* hs     = (const float*)d_in[0];
    const float* gate_w = (const float*)d_in[1];
    const float* w1     = (const float*)d_in[2];
    const float* w2     = (const float*)d_in[3];
    const float* w3     = (const float*)d_in[4];
    float* out = (float*)d_out;

    // ws layout (~103 MB). Z (needed only after gemm1) overlays the dead
    // w1b/w3b/X-prefix region during gemm2+combine.
    const size_t WSZ = (size_t)EE * FFN * CC * 2;   // 16 MB per bf16 weight
    char* ws = (char*)d_ws;
    __bf16* w2b  = (__bf16*)ws;                     // [0, 16M)   live: gemm2
    __bf16* w1b  = (__bf16*)(ws + WSZ);             // [16M,32M)  live: gemm1
    __bf16* w3b  = (__bf16*)(ws + 2 * WSZ);         // [32M,48M)  live: gemm1
    __bf16* X    = (__bf16*)(ws + 3 * WSZ);         // [48M,64M)  live: gemm1
    __bf16* Zbuf = (__bf16*)(ws + WSZ);             // overlays w1b,w3b,X-head
    __bf16* Hbuf = (__bf16*)(ws + 4 * WSZ);         // 34 MB
    char* p = ws + 4 * WSZ + (size_t)HCAP * FFN * 2;
    int*   idxl = (int*)p;            p += (size_t)EE * TT * 4;
    int*   tokE = (int*)p;            p += (size_t)TT * 4;
    int*   tokP = (int*)p;            p += (size_t)2 * TT * 4;
    float* tokW = (float*)p;          p += (size_t)2 * TT * 4;
    int*   cnt  = (int*)p;            p += 256;
    int*   off  = (int*)p;

    hipMemsetAsync(cnt, 0, EE * sizeof(int), stream);

    k_cvt<<<dim3(EE * FFN * CC / 1024, 3), 256, 0, stream>>>(
        w1, w2, w3, w1b, w2b, w3b);
    k_xpose<<<dim3(HWH / 32, CC / 32, BB), 256, 0, stream>>>(hs, X);
    k_router<<<TT / 64, 256, 0, stream>>>(hs, gate_w, cnt, idxl, tokE, tokP, tokW);
    k_offsets<<<1, 64, 0, stream>>>(cnt, off);

    k_gemm1<<<dim3(FFN / 128, TT / 128, EE), 256, 0, stream>>>(
        X, w1b, w3b, cnt, off, idxl, Hbuf);
    k_gemm2<<<dim3(CC / 128, TT / 128, EE), 256, 0, stream>>>(
        Hbuf, w2b, cnt, off, Zbuf);
    k_combine<<<dim3(TT / 32, CC / 32), 256, 0, stream>>>(
        Zbuf, off, tokE, tokP, tokW, out);
}

// Round 4
// 374.748 us; speedup vs baseline: 2.8369x; 1.1653x over previous
//
#include <hip/hip_runtime.h>
#include <hip/hip_bf16.h>
#include <math.h>

// Problem constants
#define BB 2
#define CC 1024
#define HH 64
#define WW 64
#define HWH (HH*WW)          // 4096
#define TT (BB*HWH)          // 8192 tokens
#define EE 8
#define FFN 1024
#define HCAP 17408           // sum_e ceil(cnt_e/128)*128 <= 16384 + 8*127
#define MAXTILES 136         // sum_e ceil(cnt_e/128) <= 128 + 7 (pad to 136)

typedef __bf16 bf16x8 __attribute__((ext_vector_type(8)));
typedef __bf16 bf16x4 __attribute__((ext_vector_type(4)));
typedef float  f32x4  __attribute__((ext_vector_type(4)));

// async global->LDS, 16B per lane. LDS dest = wave-uniform base + lane*16.
__device__ __forceinline__ void gl_lds16(const __bf16* g, __bf16* l) {
    __builtin_amdgcn_global_load_lds(
        (const __attribute__((address_space(1))) void*)g,
        (__attribute__((address_space(3))) void*)l, 16, 0, 0);
}

__device__ __forceinline__ void barrier_raw() {
    asm volatile("" ::: "memory");
    __builtin_amdgcn_s_barrier();
    asm volatile("" ::: "memory");
}

// ---------------------------------------------------------------------------
// k_prep: one launch doing (a) w1/w2/w3 fp32->bf16, (b) hs transpose -> X bf16,
// (c) router partial logits (16-way K-split).  All memory-bound, overlapped.
// grid: [0,12288) cvt | [12288,20480) xpose | [20480,20992) router partial
// ---------------------------------------------------------------------------
#define CVB 12288
#define XPB 8192
#define RTB 512
__global__ __launch_bounds__(256) void k_prep(
    const float* __restrict__ hs, const float* __restrict__ gate_w,
    const float* __restrict__ w1, const float* __restrict__ w2,
    const float* __restrict__ w3,
    __bf16* __restrict__ w1b, __bf16* __restrict__ w2b,
    __bf16* __restrict__ w3b, __bf16* __restrict__ X,
    float* __restrict__ logP) {
    __shared__ float sm[2112];   // union: xpose tile 32x33 | router gate 8x256
    const int bid = blockIdx.x;
    const int tid = threadIdx.x;

    if (bid < CVB) {
        // --- weight convert: 8 elems/thread ---
        const float* s; __bf16* d; int lb = bid;
        if (lb < 4096)      { s = w1; d = w1b; }
        else if (lb < 8192) { s = w2; d = w2b; lb -= 4096; }
        else                { s = w3; d = w3b; lb -= 8192; }
        const size_t i = (size_t)lb * 2048 + (size_t)tid * 8;
        const f32x4 v0 = *(const f32x4*)&s[i];
        const f32x4 v1 = *(const f32x4*)&s[i + 4];
        bf16x8 o;
#pragma unroll
        for (int j = 0; j < 4; ++j) { o[j] = (__bf16)v0[j]; o[4 + j] = (__bf16)v1[j]; }
        *(bf16x8*)&d[i] = o;
    } else if (bid < CVB + XPB) {
        // --- transpose hs (B,C,H,W) -> X [T,C] bf16 ---
        const int lb  = bid - CVB;
        const int hw0 = (lb & 127) * 32;
        const int c0  = ((lb >> 7) & 31) * 32;
        const int b   = lb >> 12;
        float (*tile)[33] = (float(*)[33])sm;
        const int tx = tid & 31, ty = tid >> 5;
        const float* src = hs + ((size_t)b * CC + c0) * HWH + hw0;
#pragma unroll
        for (int i = 0; i < 4; ++i)
            tile[ty + i * 8][tx] = src[(size_t)(ty + i * 8) * HWH + tx];
        __syncthreads();
        __bf16* dst = X + ((size_t)b * HWH + hw0) * CC + c0;
#pragma unroll
        for (int i = 0; i < 4; ++i) {
            const int hwl = ty + i * 8;
            dst[(size_t)hwl * CC + tx] = (__bf16)tile[tx][hwl];
        }
    } else {
        // --- router partial: block = (tokblk, quarter q); thread = (q2, token) ---
        const int lb  = bid - (CVB + XPB);
        const int q   = lb & 3;
        const int t64 = lb >> 2;
        float* g = sm;   // [8][256] slice of gate for channels [q*256, +256)
        for (int i = tid; i < 2048; i += 256)
            g[i] = gate_w[(size_t)(i >> 8) * CC + q * 256 + (i & 255)];
        __syncthreads();
        const int q2 = tid >> 6, tl = tid & 63;
        const int t  = t64 * 64 + tl;
        const int b  = t >> 12, hw = t & 4095;
        const float* xp = hs + (size_t)b * CC * HWH + hw;
        float l[EE];
#pragma unroll
        for (int e = 0; e < EE; ++e) l[e] = 0.0f;
        const int cbase = q * 256 + q2 * 64;
        for (int c2 = 0; c2 < 64; ++c2) {
            const float xv = xp[(size_t)(cbase + c2) * HWH];
#pragma unroll
            for (int e = 0; e < EE; ++e) l[e] += xv * g[e * 256 + q2 * 64 + c2];
        }
        float* dst = logP + ((size_t)(q * 4 + q2) * TT + t) * 8;
        f32x4 a, c;
#pragma unroll
        for (int e = 0; e < 4; ++e) { a[e] = l[e]; c[e] = l[4 + e]; }
        *(f32x4*)dst = a;
        *(f32x4*)&dst[4] = c;
    }
}

// ---------------------------------------------------------------------------
// k_top2: reduce 16 partials, top-2, renormalize, block-aggregated atomics.
// grid TT/256, block 256.
// ---------------------------------------------------------------------------
__global__ __launch_bounds__(256) void k_top2(const float* __restrict__ logP,
                                              int* __restrict__ cnt,
                                              int* __restrict__ idxl,
                                              int* __restrict__ tokE,
                                              int* __restrict__ tokP,
                                              float* __restrict__ tokW) {
    __shared__ int lcnt[EE], lbase[EE];
    const int tid = threadIdx.x;
    const int t   = blockIdx.x * 256 + tid;
    if (tid < EE) lcnt[tid] = 0;
    __syncthreads();

    float l[EE];
#pragma unroll
    for (int e = 0; e < EE; ++e) l[e] = 0.0f;
#pragma unroll
    for (int pq = 0; pq < 16; ++pq) {
        const float* src = logP + ((size_t)pq * TT + t) * 8;
        const f32x4 a = *(const f32x4*)src;
        const f32x4 c = *(const f32x4*)&src[4];
#pragma unroll
        for (int e = 0; e < 4; ++e) { l[e] += a[e]; l[4 + e] += c[e]; }
    }

    int e1 = 0; float v1 = l[0];
#pragma unroll
    for (int e = 1; e < EE; ++e) { if (l[e] > v1) { v1 = l[e]; e1 = e; } }
    int e2 = -1; float v2 = -1e30f;
#pragma unroll
    for (int e = 0; e < EE; ++e) { if (e != e1 && l[e] > v2) { v2 = l[e]; e2 = e; } }

    const float p2 = __expf(v2 - v1);
    const float rs = 1.0f / (1.0f + p2);

    const int m1 = atomicAdd(&lcnt[e1], 1);
    const int m2 = atomicAdd(&lcnt[e2], 1);
    __syncthreads();
    if (tid < EE) lbase[tid] = atomicAdd(&cnt[tid], lcnt[tid]);
    __syncthreads();
    const int p1pos = lbase[e1] + m1;
    const int p2pos = lbase[e2] + m2;

    idxl[e1 * TT + p1pos] = t;
    idxl[e2 * TT + p2pos] = t;
    tokE[t] = e1 | (e2 << 8);
    tokP[2 * t]     = p1pos;
    tokP[2 * t + 1] = p2pos;
    tokW[2 * t]     = rs;
    tokW[2 * t + 1] = p2 * rs;
}

// ---------------------------------------------------------------------------
// k_offsets: padded prefix offsets + dense (expert, m-tile) map.
// ---------------------------------------------------------------------------
__global__ void k_offsets(const int* __restrict__ cnt, int* __restrict__ off,
                          int* __restrict__ tileE, int* __restrict__ tileM,
                          int* __restrict__ nT) {
    if (threadIdx.x == 0) {
        int a = 0, n = 0;
        for (int e = 0; e < EE; ++e) {
            off[e] = a;
            const int mt = (cnt[e] + 127) >> 7;
            for (int m = 0; m < mt; ++m) { tileE[n] = e; tileM[n] = m * 128; ++n; }
            a += mt * 128;
        }
        nT[0] = n;
    }
}

// ---------------------------------------------------------------------------
// GEMM1 (sparse, grouped, double-buffered async staging, swizzled LDS):
// H = gelu(X@W1^T)*(X@W3^T), bf16.  grid (FFN/128, MAXTILES).
// ---------------------------------------------------------------------------
__global__ __launch_bounds__(256, 2)
void k_gemm1(const __bf16* __restrict__ X, const __bf16* __restrict__ w1b,
             const __bf16* __restrict__ w3b, const int* __restrict__ cnt,
             const int* __restrict__ off, const int* __restrict__ idxl,
             const int* __restrict__ tileE, const int* __restrict__ tileM,
             const int* __restrict__ nT, __bf16* __restrict__ H) {
    if ((int)blockIdx.y >= nT[0]) return;
    const int e     = tileE[blockIdx.y];
    const int mt128 = tileM[blockIdx.y];
    const int cntE  = cnt[e];
    const int goff  = off[e];
    const int n0    = blockIdx.x * 128;
    const __bf16* W1 = w1b + (size_t)e * FFN * CC;
    const __bf16* W3 = w3b + (size_t)e * FFN * CC;

    __shared__ __bf16 sA[2][128 * 32];    // 8 KB per buffer
    __shared__ __bf16 sB1[2][128 * 32];
    __shared__ __bf16 sB3[2][128 * 32];

    const int tid  = threadIdx.x;
    const int lane = tid & 63;
    const int wave = tid >> 6;
    const int wm   = (wave & 1) * 64;
    const int wn   = (wave >> 1) * 64;
    const int l15  = lane & 15;
    const int lq   = lane >> 4;
    const int rl   = lane >> 2;          // staging row within 16-row group
    const int cpos = lane & 3;
    // XOR swizzle: slot(row, c) holds global k-chunk c ^ ((row>>1)&3).
    const int c8s = (cpos ^ ((rl >> 1) & 3)) * 8;    // staging global chunk
    const int cq  = ((lq ^ ((l15 >> 1) & 3))) * 8;   // frag-read LDS chunk

    int p0 = mt128 + wave * 32 + rl;      if (p0 > cntE - 1) p0 = cntE - 1;
    int p1 = mt128 + wave * 32 + 16 + rl; if (p1 > cntE - 1) p1 = cntE - 1;
    const __bf16* ga0  = X + (size_t)idxl[e * TT + p0] * CC + c8s;
    const __bf16* ga1  = X + (size_t)idxl[e * TT + p1] * CC + c8s;
    const __bf16* gb10 = W1 + (size_t)(n0 + wave * 32 + rl) * CC + c8s;
    const __bf16* gb11 = W1 + (size_t)(n0 + wave * 32 + 16 + rl) * CC + c8s;
    const __bf16* gb30 = W3 + (size_t)(n0 + wave * 32 + rl) * CC + c8s;
    const __bf16* gb31 = W3 + (size_t)(n0 + wave * 32 + 16 + rl) * CC + c8s;
    const int lofs0 = (wave * 32) * 32;
    const int lofs1 = (wave * 32 + 16) * 32;

    f32x4 acc1[4][4] = {};
    f32x4 acc3[4][4] = {};

    auto stage = [&](int b, int kb) {
        gl_lds16(ga0 + kb,  &sA[b][lofs0]);
        gl_lds16(ga1 + kb,  &sA[b][lofs1]);
        gl_lds16(gb10 + kb, &sB1[b][lofs0]);
        gl_lds16(gb11 + kb, &sB1[b][lofs1]);
        gl_lds16(gb30 + kb, &sB3[b][lofs0]);
        gl_lds16(gb31 + kb, &sB3[b][lofs1]);
    };

    stage(0, 0);
    int p = 0;
    for (int kb = 0; kb < CC; kb += 32, p ^= 1) {
        if (kb + 32 < CC) {
            stage(p ^ 1, kb + 32);
            asm volatile("s_waitcnt vmcnt(6)" ::: "memory");  // buf p landed
        } else {
            asm volatile("s_waitcnt vmcnt(0)" ::: "memory");
        }
        barrier_raw();   // all waves' buf-p loads complete

        bf16x8 af[4], b1f[4], b3f[4];
#pragma unroll
        for (int i = 0; i < 4; ++i)
            af[i] = *(const bf16x8*)&sA[p][(wm + i * 16 + l15) * 32 + cq];
#pragma unroll
        for (int j = 0; j < 4; ++j)
            b1f[j] = *(const bf16x8*)&sB1[p][(wn + j * 16 + l15) * 32 + cq];
#pragma unroll
        for (int j = 0; j < 4; ++j)
            b3f[j] = *(const bf16x8*)&sB3[p][(wn + j * 16 + l15) * 32 + cq];
        asm volatile("s_waitcnt lgkmcnt(0)" ::: "memory");  // my frags in regs
        barrier_raw();   // all waves done reading buf p -> next iter may clobber

#pragma unroll
        for (int i = 0; i < 4; ++i)
#pragma unroll
            for (int j = 0; j < 4; ++j) {
                acc1[i][j] = __builtin_amdgcn_mfma_f32_16x16x32_bf16(
                    af[i], b1f[j], acc1[i][j], 0, 0, 0);
                acc3[i][j] = __builtin_amdgcn_mfma_f32_16x16x32_bf16(
                    af[i], b3f[j], acc3[i][j], 0, 0, 0);
            }
    }

    // epilogue: exact gelu * w3-branch -> packed H rows
#pragma unroll
    for (int i = 0; i < 4; ++i) {
        const int gb = goff + mt128 + wm + i * 16 + lq * 4;
#pragma unroll
        for (int j = 0; j < 4; ++j) {
            const int nb = n0 + wn + j * 16 + l15;
#pragma unroll
            for (int r = 0; r < 4; ++r) {
                const float a  = acc1[i][j][r];
                const float c  = acc3[i][j][r];
                const float ge = 0.5f * a * (1.0f + erff(a * 0.70710678118654752f));
                H[(size_t)(gb + r) * FFN + nb] = (__bf16)(ge * c);
            }
        }
    }
}

// ---------------------------------------------------------------------------
// GEMM2 (sparse, grouped, double-buffered, swizzled): Z = H @ W2^T, bf16.
// grid (C/128, MAXTILES)
// ---------------------------------------------------------------------------
__global__ __launch_bounds__(256, 2)
void k_gemm2(const __bf16* __restrict__ H, const __bf16* __restrict__ w2b,
             const int* __restrict__ off, const int* __restrict__ tileE,
             const int* __restrict__ tileM, const int* __restrict__ nT,
             __bf16* __restrict__ Z) {
    if ((int)blockIdx.y >= nT[0]) return;
    const int e     = tileE[blockIdx.y];
    const int mt128 = tileM[blockIdx.y];
    const int goff  = off[e];
    const int n0    = blockIdx.x * 128;
    const __bf16* W2 = w2b + (size_t)e * CC * FFN;
    const __bf16* Arows = H + (size_t)(goff + mt128) * FFN;

    __shared__ __bf16 sA[2][128 * 32];
    __shared__ __bf16 sB[2][128 * 32];

    const int tid  = threadIdx.x;
    const int lane = tid & 63;
    const int wave = tid >> 6;
    const int wm   = (wave & 1) * 64;
    const int wn   = (wave >> 1) * 64;
    const int l15  = lane & 15;
    const int lq   = lane >> 4;
    const int rl   = lane >> 2;
    const int cpos = lane & 3;
    const int c8s = (cpos ^ ((rl >> 1) & 3)) * 8;
    const int cq  = ((lq ^ ((l15 >> 1) & 3))) * 8;

    const __bf16* ga0 = Arows + (size_t)(wave * 32 + rl) * FFN + c8s;
    const __bf16* ga1 = Arows + (size_t)(wave * 32 + 16 + rl) * FFN + c8s;
    const __bf16* gb0 = W2 + (size_t)(n0 + wave * 32 + rl) * FFN + c8s;
    const __bf16* gb1 = W2 + (size_t)(n0 + wave * 32 + 16 + rl) * FFN + c8s;
    const int lofs0 = (wave * 32) * 32;
    const int lofs1 = (wave * 32 + 16) * 32;

    f32x4 acc[4][4] = {};

    auto stage = [&](int b, int kb) {
        gl_lds16(ga0 + kb, &sA[b][lofs0]);
        gl_lds16(ga1 + kb, &sA[b][lofs1]);
        gl_lds16(gb0 + kb, &sB[b][lofs0]);
        gl_lds16(gb1 + kb, &sB[b][lofs1]);
    };

    stage(0, 0);
    int p = 0;
    for (int kb = 0; kb < FFN; kb += 32, p ^= 1) {
        if (kb + 32 < FFN) {
            stage(p ^ 1, kb + 32);
            asm volatile("s_waitcnt vmcnt(4)" ::: "memory");
        } else {
            asm volatile("s_waitcnt vmcnt(0)" ::: "memory");
        }
        barrier_raw();

        bf16x8 af[4], bf[4];
#pragma unroll
        for (int i = 0; i < 4; ++i)
            af[i] = *(const bf16x8*)&sA[p][(wm + i * 16 + l15) * 32 + cq];
#pragma unroll
        for (int j = 0; j < 4; ++j)
            bf[j] = *(const bf16x8*)&sB[p][(wn + j * 16 + l15) * 32 + cq];
        asm volatile("s_waitcnt lgkmcnt(0)" ::: "memory");
        barrier_raw();

#pragma unroll
        for (int i = 0; i < 4; ++i)
#pragma unroll
            for (int j = 0; j < 4; ++j)
                acc[i][j] = __builtin_amdgcn_mfma_f32_16x16x32_bf16(
                    af[i], bf[j], acc[i][j], 0, 0, 0);
    }

#pragma unroll
    for (int i = 0; i < 4; ++i) {
        const int gb = goff + mt128 + wm + i * 16 + lq * 4;
#pragma unroll
        for (int j = 0; j < 4; ++j) {
            const int c = n0 + wn + j * 16 + l15;
#pragma unroll
            for (int r = 0; r < 4; ++r)
                Z[(size_t)(gb + r) * CC + c] = (__bf16)acc[i][j][r];
        }
    }
}

// ---------------------------------------------------------------------------
// k_combine: out[t,c] = w1*Z[r1,c] + w2*Z[r2,c], transposed to (B,C,H,W).
// ---------------------------------------------------------------------------
__global__ __launch_bounds__(256) void k_combine(const __bf16* __restrict__ Z,
                                                 const int* __restrict__ off,
                                                 const int* __restrict__ tokE,
                                                 const int* __restrict__ tokP,
                                                 const float* __restrict__ tokW,
                                                 float* __restrict__ out) {
    __shared__ float tile[32][33];
    const int t0 = blockIdx.x * 32;
    const int c0 = blockIdx.y * 32;
    const int tx = threadIdx.x & 31;
    const int ty = threadIdx.x >> 5;

#pragma unroll
    for (int i = 0; i < 4; ++i) {
        const int tl = ty + 8 * i;
        const int t  = t0 + tl;
        const int ee = tokE[t];
        const int e1 = ee & 0xff, e2 = ee >> 8;
        const int r1 = off[e1] + tokP[2 * t];
        const int r2 = off[e2] + tokP[2 * t + 1];
        const float v = tokW[2 * t]     * (float)Z[(size_t)r1 * CC + c0 + tx]
                      + tokW[2 * t + 1] * (float)Z[(size_t)r2 * CC + c0 + tx];
        tile[tl][tx] = v;
    }
    __syncthreads();

    const int b   = t0 >> 12;
    const int hw0 = t0 & 4095;
#pragma unroll
    for (int i = 0; i < 4; ++i) {
        const int cl = ty + 8 * i;
        out[(size_t)b * CC * HWH + (size_t)(c0 + cl) * HWH + hw0 + tx] = tile[tx][cl];
    }
}

// ---------------------------------------------------------------------------
extern "C" void kernel_launch(void* const* d_in, const int* in_sizes, int n_in,
                              void* d_out, int out_size, void* d_ws, size_t ws_size,
                              hipStream_t stream) {
    const float* hs     = (const float*)d_in[0];
    const float* gate_w = (const float*)d_in[1];
    const float* w1     = (const float*)d_in[2];
    const float* w2     = (const float*)d_in[3];
    const float* w3     = (const float*)d_in[4];
    float* out = (float*)d_out;

    // ws layout (~100.5 MB). logP overlays Hbuf (dead until gemm1);
    // Zbuf overlays w1b/w3b/X-head (dead after gemm1).
    const size_t WSZ = (size_t)EE * FFN * CC * 2;   // 16 MB per bf16 weight
    char* ws = (char*)d_ws;
    __bf16* w2b  = (__bf16*)ws;                     // [0, 16M)   live: gemm2
    __bf16* w1b  = (__bf16*)(ws + WSZ);             // [16M,32M)  live: gemm1
    __bf16* w3b  = (__bf16*)(ws + 2 * WSZ);         // [32M,48M)  live: gemm1
    __bf16* X    = (__bf16*)(ws + 3 * WSZ);         // [48M,64M)  live: gemm1
    __bf16* Zbuf = (__bf16*)(ws + WSZ);             // overlays w1b,w3b,X-head
    __bf16* Hbuf = (__bf16*)(ws + 4 * WSZ);         // 34 MB
    float*  logP = (float*)Hbuf;                    // 4 MB, dead before gemm1
    char* p = ws + 4 * WSZ + (size_t)HCAP * FFN * 2;
    int*   idxl  = (int*)p;           p += (size_t)EE * TT * 4;
    int*   tokE  = (int*)p;           p += (size_t)TT * 4;
    int*   tokP  = (int*)p;           p += (size_t)2 * TT * 4;
    float* tokW  = (float*)p;         p += (size_t)2 * TT * 4;
    int*   cnt   = (int*)p;           p += 256;
    int*   off   = (int*)p;           p += 256;
    int*   tileE = (int*)p;           p += MAXTILES * 4;
    int*   tileM = (int*)p;           p += MAXTILES * 4;
    int*   nT    = (int*)p;

    hipMemsetAsync(cnt, 0, EE * sizeof(int), stream);

    k_prep<<<CVB + XPB + RTB, 256, 0, stream>>>(
        hs, gate_w, w1, w2, w3, w1b, w2b, w3b, X, logP);
    k_top2<<<TT / 256, 256, 0, stream>>>(logP, cnt, idxl, tokE, tokP, tokW);
    k_offsets<<<1, 64, 0, stream>>>(cnt, off, tileE, tileM, nT);

    k_gemm1<<<dim3(FFN / 128, MAXTILES), 256, 0, stream>>>(
        X, w1b, w3b, cnt, off, idxl, tileE, tileM, nT, Hbuf);
    k_gemm2<<<dim3(CC / 128, MAXTILES), 256, 0, stream>>>(
        Hbuf, w2b, off, tileE, tileM, nT, Zbuf);
    k_combine<<<dim3(TT / 32, CC / 32), 256, 0, stream>>>(
        Zbuf, off, tokE, tokP, tokW, out);
}